// Round 2
// baseline (320.523 us; speedup 1.0000x reference)
//
#include <hip/hip_runtime.h>

#define BB 4
#define AA 100000
#define MM 32
#define NC 80

// ws layout (bytes):
//   [0..3]   float cls_sum
//   [4..7]   float reg_sum
//   [8..11]  uint  pos_count
//   [12..15] uint  valid_count (compacted-list append cursor)
//   [16.. )  uint  list[BB*AA]  packed entries: (anchor_id << 7) | (code+1)
//            code: -1 = valid negative, 0..79 = positive class. Excluded anchors not listed.

#define INVALID_ENTRY 0xFFFFFFFFu

__global__ __launch_bounds__(256) void targets_kernel(
    const float* __restrict__ anchors,      // AA*4
    const float* __restrict__ annotations,  // BB*MM*5
    const float* __restrict__ regression,   // BB*AA*4
    float* __restrict__ acc,
    unsigned* __restrict__ list)
{
    __shared__ float ann[MM * 5];
    const int b = blockIdx.y;
    const int tid = threadIdx.x;
    if (tid < MM * 5) ann[tid] = annotations[b * MM * 5 + tid];
    __syncthreads();

    const int a = blockIdx.x * blockDim.x + tid;
    float reg_sum = 0.0f;
    int pos_cnt = 0;
    bool valid = false;
    int code = -1;   // -1 = negative, 0..79 = positive class

    if (a < AA) {
        const float ax1 = anchors[a * 4 + 0];
        const float ay1 = anchors[a * 4 + 1];
        const float ax2 = anchors[a * 4 + 2];
        const float ay2 = anchors[a * 4 + 3];
        // exact IEEE ops (no FMA contraction) so pos/ignore thresholds match numpy bit-for-bit:
        const float area_a = __fmul_rn(__fsub_rn(ax2, ax1), __fsub_rn(ay2, ay1));

        float best_iou = -1.0f;
        int best = 0;
        #pragma unroll
        for (int j = 0; j < MM; ++j) {
            const float bx1 = ann[j * 5 + 0];
            const float by1 = ann[j * 5 + 1];
            const float bx2 = ann[j * 5 + 2];
            const float by2 = ann[j * 5 + 3];
            const float ix1 = fmaxf(ax1, bx1);
            const float iy1 = fmaxf(ay1, by1);
            const float ix2 = fminf(ax2, bx2);
            const float iy2 = fminf(ay2, by2);
            const float iw = fmaxf(__fsub_rn(ix2, ix1), 0.0f);
            const float ih = fmaxf(__fsub_rn(iy2, iy1), 0.0f);
            const float inter = __fmul_rn(iw, ih);
            const float area_b = __fmul_rn(__fsub_rn(bx2, bx1), __fsub_rn(by2, by1));
            const float uni = __fsub_rn(__fadd_rn(area_a, area_b), inter);
            const float iou = __fdiv_rn(inter, fmaxf(uni, 1e-8f));
            if (iou > best_iou) { best_iou = iou; best = j; }  // strict > keeps first max (argmax)
        }

        const bool pos = best_iou >= 0.5f;
        const bool ign = (best_iou > 0.4f) && !pos;
        const float cx = (ax1 + ax2) * 0.5f;
        const float cy = (ay1 + ay2) * 0.5f;
        const bool inside = (cx >= 0.0f) && (cx < 800.0f) && (cy >= 0.0f) && (cy < 800.0f);

        valid = inside && !ign;                 // state != -1
        if (valid && pos) code = (int)ann[best * 5 + 4];

        const bool pos_eff = pos && inside;     // state == 1
        if (pos_eff) {
            pos_cnt = 1;
            const float aw = ax2 - ax1;
            const float ah = ay2 - ay1;
            const float bx1 = ann[best * 5 + 0];
            const float by1 = ann[best * 5 + 1];
            const float bx2 = ann[best * 5 + 2];
            const float by2 = ann[best * 5 + 3];
            float t[4];
            t[0] = ((bx1 - ax1) / aw) / 0.2f;
            t[1] = ((by1 - ay1) / ah) / 0.2f;
            t[2] = ((bx2 - ax2) / aw) / 0.2f;
            t[3] = ((by2 - ay2) / ah) / 0.2f;
            const float* rg = regression + (((size_t)b * AA + a) * 4);
            #pragma unroll
            for (int k = 0; k < 4; ++k) {
                const float d = fabsf(rg[k] - t[k]);
                const float l1 = (d < (1.0f / 9.0f)) ? (4.5f * d * d) : (d - (0.5f / 9.0f));
                reg_sum += l1;
            }
        }
    }

    // ---- wave-aggregated compaction append (one atomic per wave) ----
    const int lane = tid & 63;
    const unsigned long long m = __ballot(valid);
    const int cnt = __popcll(m);
    unsigned base = 0;
    if (lane == 0 && cnt) base = atomicAdd((unsigned*)acc + 3, (unsigned)cnt);
    base = __shfl(base, 0);
    if (valid) {
        const unsigned off = (unsigned)__popcll(m & ((1ULL << lane) - 1ULL));
        list[base + off] = ((unsigned)(b * AA + a) << 7) | (unsigned)(code + 1);
    }

    // ---- reg loss + pos count reduction ----
    #pragma unroll
    for (int off = 32; off > 0; off >>= 1) {
        reg_sum += __shfl_down(reg_sum, off);
        pos_cnt += __shfl_down(pos_cnt, off);
    }
    __shared__ float wsum[4];
    __shared__ int   wcnt[4];
    const int wave = tid >> 6;
    if (lane == 0) { wsum[wave] = reg_sum; wcnt[wave] = pos_cnt; }
    __syncthreads();
    if (tid == 0) {
        atomicAdd(&acc[1], wsum[0] + wsum[1] + wsum[2] + wsum[3]);
        atomicAdd((unsigned*)acc + 2, (unsigned)(wcnt[0] + wcnt[1] + wcnt[2] + wcnt[3]));
    }
}

__global__ __launch_bounds__(256) void focal_kernel(
    const float* __restrict__ cls,       // BB*AA*NC, read as float4
    const unsigned* __restrict__ list,   // compacted entries
    float* __restrict__ acc)
{
    const unsigned V = ((const unsigned*)acc)[3];       // valid count (from targets)
    __shared__ unsigned sidx[256];
    float sum = 0.0f;

    const unsigned nchunk = (V + 255u) >> 8;
    for (unsigned chunk = blockIdx.x; chunk < nchunk; chunk += gridDim.x) {
        const unsigned slot = (chunk << 8) + threadIdx.x;
        __syncthreads();   // protect sidx reuse across chunks
        sidx[threadIdx.x] = (slot < V) ? list[slot] : INVALID_ENTRY;
        __syncthreads();

        // 256 anchors * 20 float4 = 5120 float4 loads, 20 per thread, all
        // index-dependent only on LDS (fast) -> deep global-load pipeline.
        #pragma unroll
        for (int r = 0; r < 20; ++r) {
            const int flat = r * 256 + (int)threadIdx.x;
            const int s    = flat / 20;        // slot within chunk
            const int comp = flat - s * 20;    // which float4 of the anchor
            const unsigned e = sidx[s];
            if (e != INVALID_ENTRY) {
                const unsigned anchor = e >> 7;
                const int pcode = (int)(e & 127u) - 1;    // -1 = negative
                const float4 v = ((const float4*)cls)[(size_t)anchor * 20 + comp];
                const int colbase = comp * 4;
                const float px[4] = { v.x, v.y, v.z, v.w };
                #pragma unroll
                for (int j = 0; j < 4; ++j) {
                    const float p = fminf(fmaxf(px[j], 1e-4f), 0.9999f);
                    const float onem = 1.0f - p;
                    float val = 0.75f * p * p * (-__logf(onem));       // label==0
                    if (pcode == colbase + j)
                        val = 0.25f * onem * onem * (-__logf(p));      // label==1
                    sum += val;
                }
            }
        }
    }

    #pragma unroll
    for (int off = 32; off > 0; off >>= 1) sum += __shfl_down(sum, off);
    __shared__ float wsum[4];
    const int wave = threadIdx.x >> 6, lane = threadIdx.x & 63;
    if (lane == 0) wsum[wave] = sum;
    __syncthreads();
    if (threadIdx.x == 0) atomicAdd(&acc[0], wsum[0] + wsum[1] + wsum[2] + wsum[3]);
}

__global__ void finalize_kernel(const float* __restrict__ acc, float* __restrict__ out)
{
    const float np = fmaxf((float)(*((const unsigned*)acc + 2)), 1.0f);
    out[0] = (acc[0] + acc[1]) / np;
}

extern "C" void kernel_launch(void* const* d_in, const int* in_sizes, int n_in,
                              void* d_out, int out_size, void* d_ws, size_t ws_size,
                              hipStream_t stream)
{
    const float* classification = (const float*)d_in[0];  // BB*AA*NC
    const float* regression     = (const float*)d_in[1];  // BB*AA*4
    const float* anchors        = (const float*)d_in[2];  // AA*4
    const float* annotations    = (const float*)d_in[3];  // BB*MM*5
    float* out = (float*)d_out;

    float* acc = (float*)d_ws;
    unsigned* list = (unsigned*)((char*)d_ws + 16);

    // ws is poisoned to 0xAA before every timed launch — zero the accumulators.
    hipMemsetAsync(d_ws, 0, 16, stream);

    dim3 gA((AA + 255) / 256, BB);
    targets_kernel<<<gA, 256, 0, stream>>>(anchors, annotations, regression, acc, list);

    focal_kernel<<<1024, 256, 0, stream>>>(classification, list, acc);

    finalize_kernel<<<1, 1, 0, stream>>>(acc, out);
}

// Round 3
// 211.081 us; speedup vs baseline: 1.5185x; 1.5185x over previous
//
#include <hip/hip_runtime.h>

#define BB 4
#define AA 100000
#define MM 32
#define NC 80
#define GX 391               // ceil(AA/256)
#define NBLK (GX * BB)       // 1564 blocks

// ws layout (floats): cls_part[NBLK] | reg_part[NBLK] | pos_part[NBLK] (as uint)
// All partials are written unconditionally by every block -> no zero-init, no atomics.

__global__ __launch_bounds__(256) void fused_kernel(
    const float* __restrict__ anchors,      // AA*4
    const float* __restrict__ annotations,  // BB*MM*5
    const float* __restrict__ regression,   // BB*AA*4
    const float* __restrict__ cls,          // BB*AA*NC, read as float4
    float* __restrict__ cls_part,
    float* __restrict__ reg_part,
    unsigned* __restrict__ pos_part)
{
    __shared__ float ann[MM * 5];
    __shared__ int scode[256];   // -2 = excluded/ignored/invalid, -1 = valid negative, 0..79 = positive class
    const int b = blockIdx.y;
    const int tid = threadIdx.x;
    if (tid < MM * 5) ann[tid] = annotations[b * MM * 5 + tid];
    __syncthreads();

    const int abase = blockIdx.x * 256;
    const int a = abase + tid;
    float reg_sum = 0.0f;
    int pos_cnt = 0;
    int code = -2;

    if (a < AA) {
        const float ax1 = anchors[a * 4 + 0];
        const float ay1 = anchors[a * 4 + 1];
        const float ax2 = anchors[a * 4 + 2];
        const float ay2 = anchors[a * 4 + 3];
        // exact IEEE ops (no FMA contraction) so pos/ignore thresholds match numpy bit-for-bit:
        const float area_a = __fmul_rn(__fsub_rn(ax2, ax1), __fsub_rn(ay2, ay1));

        float best_iou = -1.0f;
        int best = 0;
        #pragma unroll
        for (int j = 0; j < MM; ++j) {
            const float bx1 = ann[j * 5 + 0];
            const float by1 = ann[j * 5 + 1];
            const float bx2 = ann[j * 5 + 2];
            const float by2 = ann[j * 5 + 3];
            const float ix1 = fmaxf(ax1, bx1);
            const float iy1 = fmaxf(ay1, by1);
            const float ix2 = fminf(ax2, bx2);
            const float iy2 = fminf(ay2, by2);
            const float iw = fmaxf(__fsub_rn(ix2, ix1), 0.0f);
            const float ih = fmaxf(__fsub_rn(iy2, iy1), 0.0f);
            const float inter = __fmul_rn(iw, ih);
            const float area_b = __fmul_rn(__fsub_rn(bx2, bx1), __fsub_rn(by2, by1));
            const float uni = __fsub_rn(__fadd_rn(area_a, area_b), inter);
            const float iou = __fdiv_rn(inter, fmaxf(uni, 1e-8f));
            if (iou > best_iou) { best_iou = iou; best = j; }  // strict > keeps first max (argmax)
        }

        const bool pos = best_iou >= 0.5f;
        const bool ign = (best_iou > 0.4f) && !pos;
        const float cx = (ax1 + ax2) * 0.5f;
        const float cy = (ay1 + ay2) * 0.5f;
        const bool inside = (cx >= 0.0f) && (cx < 800.0f) && (cy >= 0.0f) && (cy < 800.0f);

        const bool valid = inside && !ign;      // state != -1
        if (valid) code = pos ? (int)ann[best * 5 + 4] : -1;

        if (pos && inside) {                    // state == 1
            pos_cnt = 1;
            const float aw = ax2 - ax1;
            const float ah = ay2 - ay1;
            const float bx1 = ann[best * 5 + 0];
            const float by1 = ann[best * 5 + 1];
            const float bx2 = ann[best * 5 + 2];
            const float by2 = ann[best * 5 + 3];
            float t[4];
            t[0] = ((bx1 - ax1) / aw) / 0.2f;
            t[1] = ((by1 - ay1) / ah) / 0.2f;
            t[2] = ((bx2 - ax2) / aw) / 0.2f;
            t[3] = ((by2 - ay2) / ah) / 0.2f;
            const float* rg = regression + (((size_t)b * AA + a) * 4);
            #pragma unroll
            for (int k = 0; k < 4; ++k) {
                const float d = fabsf(rg[k] - t[k]);
                reg_sum += (d < (1.0f / 9.0f)) ? (4.5f * d * d) : (d - (0.5f / 9.0f));
            }
        }
    }
    scode[tid] = code;
    __syncthreads();

    // ---- focal phase: 256 anchors * 20 float4 = 5120 loads, 20/thread.
    // flat = r*256+tid -> consecutive threads hit consecutive float4s (coalesced).
    // Indices come from LDS only -> loads pipeline deeply; excluded anchors skip the load.
    float csum = 0.0f;
    const size_t img_base = ((size_t)b * AA + abase) * 20;
    #pragma unroll
    for (int r = 0; r < 20; ++r) {
        const int flat = r * 256 + tid;
        const int s    = flat / 20;          // magic-mul
        const int comp = flat - s * 20;
        const int c = scode[s];
        if (c != -2) {
            const float4 v = ((const float4*)cls)[img_base + (size_t)s * 20 + comp];
            const int colbase = comp * 4;
            const float px[4] = { v.x, v.y, v.z, v.w };
            #pragma unroll
            for (int j = 0; j < 4; ++j) {
                const float p = fminf(fmaxf(px[j], 1e-4f), 0.9999f);
                const float onem = 1.0f - p;
                float val = 0.75f * p * p * (-__logf(onem));       // label==0
                if (c == colbase + j)
                    val = 0.25f * onem * onem * (-__logf(p));      // label==1 (rare)
                csum += val;
            }
        }
    }

    // ---- block reduction (wave shuffle + LDS), plain stores, no atomics ----
    #pragma unroll
    for (int off = 32; off > 0; off >>= 1) {
        csum    += __shfl_down(csum, off);
        reg_sum += __shfl_down(reg_sum, off);
        pos_cnt += __shfl_down(pos_cnt, off);
    }
    __shared__ float wc[4], wr[4];
    __shared__ int   wp[4];
    const int wave = tid >> 6, lane = tid & 63;
    if (lane == 0) { wc[wave] = csum; wr[wave] = reg_sum; wp[wave] = pos_cnt; }
    __syncthreads();
    if (tid == 0) {
        const int idx = b * GX + blockIdx.x;
        cls_part[idx] = wc[0] + wc[1] + wc[2] + wc[3];
        reg_part[idx] = wr[0] + wr[1] + wr[2] + wr[3];
        pos_part[idx] = (unsigned)(wp[0] + wp[1] + wp[2] + wp[3]);
    }
}

__global__ __launch_bounds__(256) void finalize_kernel(
    const float* __restrict__ cls_part,
    const float* __restrict__ reg_part,
    const unsigned* __restrict__ pos_part,
    float* __restrict__ out)
{
    float cs = 0.0f, rs = 0.0f;
    unsigned pc = 0;
    for (int i = threadIdx.x; i < NBLK; i += 256) {
        cs += cls_part[i];
        rs += reg_part[i];
        pc += pos_part[i];
    }
    #pragma unroll
    for (int off = 32; off > 0; off >>= 1) {
        cs += __shfl_down(cs, off);
        rs += __shfl_down(rs, off);
        pc += __shfl_down(pc, off);
    }
    __shared__ float wc[4], wr[4];
    __shared__ unsigned wp[4];
    const int wave = threadIdx.x >> 6, lane = threadIdx.x & 63;
    if (lane == 0) { wc[wave] = cs; wr[wave] = rs; wp[wave] = pc; }
    __syncthreads();
    if (threadIdx.x == 0) {
        const float csum = wc[0] + wc[1] + wc[2] + wc[3];
        const float rsum = wr[0] + wr[1] + wr[2] + wr[3];
        const float np = fmaxf((float)(wp[0] + wp[1] + wp[2] + wp[3]), 1.0f);
        out[0] = (csum + rsum) / np;
    }
}

extern "C" void kernel_launch(void* const* d_in, const int* in_sizes, int n_in,
                              void* d_out, int out_size, void* d_ws, size_t ws_size,
                              hipStream_t stream)
{
    const float* classification = (const float*)d_in[0];  // BB*AA*NC
    const float* regression     = (const float*)d_in[1];  // BB*AA*4
    const float* anchors        = (const float*)d_in[2];  // AA*4
    const float* annotations    = (const float*)d_in[3];  // BB*MM*5
    float* out = (float*)d_out;

    float*    cls_part = (float*)d_ws;
    float*    reg_part = cls_part + NBLK;
    unsigned* pos_part = (unsigned*)(reg_part + NBLK);

    dim3 grid(GX, BB);
    fused_kernel<<<grid, 256, 0, stream>>>(anchors, annotations, regression,
                                           classification, cls_part, reg_part, pos_part);
    finalize_kernel<<<1, 256, 0, stream>>>(cls_part, reg_part, pos_part, out);
}

// Round 4
// 207.470 us; speedup vs baseline: 1.5449x; 1.0174x over previous
//
#include <hip/hip_runtime.h>

#define BB 4
#define AA 100000
#define MM 32
#define NC 80
#define GX 391               // ceil(AA/256)
#define NBLK (GX * BB)       // 1564 blocks

// ws layout (floats): cls_part[NBLK] | reg_part[NBLK] | pos_part[NBLK] (as uint)
// All partials written unconditionally by every block -> no zero-init, no atomics.

__global__ __launch_bounds__(256) void fused_kernel(
    const float* __restrict__ anchors,      // AA*4
    const float* __restrict__ annotations,  // BB*MM*5
    const float* __restrict__ regression,   // BB*AA*4
    const float* __restrict__ cls,          // BB*AA*NC, read as float4
    float* __restrict__ cls_part,
    float* __restrict__ reg_part,
    unsigned* __restrict__ pos_part)
{
    __shared__ float ann[MM * 5];
    __shared__ int scode[256];   // -2 = excluded, -1 = valid negative, 0..79 = positive class
    const int b = blockIdx.y;
    const int tid = threadIdx.x;
    if (tid < MM * 5) ann[tid] = annotations[b * MM * 5 + tid];
    __syncthreads();

    const int abase = blockIdx.x * 256;
    const int a = abase + tid;
    float reg_sum = 0.0f;
    int pos_cnt = 0;
    int code = -2;

    if (a < AA) {
        const float4 an = ((const float4*)anchors)[a];
        const float ax1 = an.x, ay1 = an.y, ax2 = an.z, ay2 = an.w;
        // exact IEEE ops (no FMA contraction) so pos/ignore thresholds match numpy bit-for-bit:
        const float area_a = __fmul_rn(__fsub_rn(ax2, ax1), __fsub_rn(ay2, ay1));

        float best_iou = -1.0f;
        int best = 0;
        #pragma unroll
        for (int j = 0; j < MM; ++j) {
            const float bx1 = ann[j * 5 + 0];
            const float by1 = ann[j * 5 + 1];
            const float bx2 = ann[j * 5 + 2];
            const float by2 = ann[j * 5 + 3];
            const float ix1 = fmaxf(ax1, bx1);
            const float iy1 = fmaxf(ay1, by1);
            const float ix2 = fminf(ax2, bx2);
            const float iy2 = fminf(ay2, by2);
            const float iw = fmaxf(__fsub_rn(ix2, ix1), 0.0f);
            const float ih = fmaxf(__fsub_rn(iy2, iy1), 0.0f);
            const float inter = __fmul_rn(iw, ih);
            const float area_b = __fmul_rn(__fsub_rn(bx2, bx1), __fsub_rn(by2, by1));
            const float uni = __fsub_rn(__fadd_rn(area_a, area_b), inter);
            const float iou = __fdiv_rn(inter, fmaxf(uni, 1e-8f));
            if (iou > best_iou) { best_iou = iou; best = j; }  // strict > keeps first max (argmax)
        }

        const bool pos = best_iou >= 0.5f;
        const bool ign = (best_iou > 0.4f) && !pos;
        const float cx = (ax1 + ax2) * 0.5f;
        const float cy = (ay1 + ay2) * 0.5f;
        const bool inside = (cx >= 0.0f) && (cx < 800.0f) && (cy >= 0.0f) && (cy < 800.0f);

        const bool valid = inside && !ign;      // state != -1
        if (valid) code = pos ? (int)ann[best * 5 + 4] : -1;

        if (pos && inside) {                    // state == 1
            pos_cnt = 1;
            const float aw = ax2 - ax1;
            const float ah = ay2 - ay1;
            const float bx1 = ann[best * 5 + 0];
            const float by1 = ann[best * 5 + 1];
            const float bx2 = ann[best * 5 + 2];
            const float by2 = ann[best * 5 + 3];
            float t[4];
            t[0] = ((bx1 - ax1) / aw) / 0.2f;
            t[1] = ((by1 - ay1) / ah) / 0.2f;
            t[2] = ((bx2 - ax2) / aw) / 0.2f;
            t[3] = ((by2 - ay2) / ah) / 0.2f;
            const float* rg = regression + (((size_t)b * AA + a) * 4);
            #pragma unroll
            for (int k = 0; k < 4; ++k) {
                const float d = fabsf(rg[k] - t[k]);
                reg_sum += (d < (1.0f / 9.0f)) ? (4.5f * d * d) : (d - (0.5f / 9.0f));
            }
        }
    }
    scode[tid] = code;
    __syncthreads();

    // ---- focal phase ----
    // Block's 256 anchors own 5120 contiguous float4s starting at img_base; thread t,
    // step r handles flat = r*256+t (coalesced). Loads are UNCONDITIONAL in exec —
    // excluded anchors read base4[0] (L1 broadcast, no HBM cost) via address select —
    // and issued in batches of 5 with no consumer in between, so 5 loads/wave stay
    // in flight (no per-iteration s_waitcnt vmcnt(0) chain).
    float csum = 0.0f;
    const float4* base4 = (const float4*)cls + ((size_t)b * AA + abase) * 20;
    #pragma unroll
    for (int batch = 0; batch < 4; ++batch) {
        float4 v[5];
        int cc[5], colb[5];
        #pragma unroll
        for (int k = 0; k < 5; ++k) {
            const int flat = (batch * 5 + k) * 256 + tid;
            const int s = flat / 20;             // magic-mul
            cc[k] = scode[s];
            colb[k] = (flat - s * 20) * 4;
            const float4* addr = (cc[k] != -2) ? (base4 + flat) : base4;  // dummy-but-valid
            v[k] = *addr;
        }
        #pragma unroll
        for (int k = 0; k < 5; ++k) {
            const float m = (cc[k] != -2) ? 1.0f : 0.0f;
            const float px[4] = { v[k].x, v[k].y, v[k].z, v[k].w };
            float sub = 0.0f;
            #pragma unroll
            for (int j = 0; j < 4; ++j) {
                const float p = fminf(fmaxf(px[j], 1e-4f), 0.9999f);
                const float onem = 1.0f - p;
                float val = 0.75f * p * p * (-__logf(onem));       // label==0
                if (cc[k] == colb[k] + j)
                    val = 0.25f * onem * onem * (-__logf(p));      // label==1 (rare)
                sub += val;
            }
            csum += m * sub;
        }
    }

    // ---- block reduction (wave shuffle + LDS), plain stores, no atomics ----
    #pragma unroll
    for (int off = 32; off > 0; off >>= 1) {
        csum    += __shfl_down(csum, off);
        reg_sum += __shfl_down(reg_sum, off);
        pos_cnt += __shfl_down(pos_cnt, off);
    }
    __shared__ float wc[4], wr[4];
    __shared__ int   wp[4];
    const int wave = tid >> 6, lane = tid & 63;
    if (lane == 0) { wc[wave] = csum; wr[wave] = reg_sum; wp[wave] = pos_cnt; }
    __syncthreads();
    if (tid == 0) {
        const int idx = b * GX + blockIdx.x;
        cls_part[idx] = wc[0] + wc[1] + wc[2] + wc[3];
        reg_part[idx] = wr[0] + wr[1] + wr[2] + wr[3];
        pos_part[idx] = (unsigned)(wp[0] + wp[1] + wp[2] + wp[3]);
    }
}

__global__ __launch_bounds__(256) void finalize_kernel(
    const float* __restrict__ cls_part,
    const float* __restrict__ reg_part,
    const unsigned* __restrict__ pos_part,
    float* __restrict__ out)
{
    float cs = 0.0f, rs = 0.0f;
    unsigned pc = 0;
    for (int i = threadIdx.x; i < NBLK; i += 256) {
        cs += cls_part[i];
        rs += reg_part[i];
        pc += pos_part[i];
    }
    #pragma unroll
    for (int off = 32; off > 0; off >>= 1) {
        cs += __shfl_down(cs, off);
        rs += __shfl_down(rs, off);
        pc += __shfl_down(pc, off);
    }
    __shared__ float wc[4], wr[4];
    __shared__ unsigned wp[4];
    const int wave = threadIdx.x >> 6, lane = threadIdx.x & 63;
    if (lane == 0) { wc[wave] = cs; wr[wave] = rs; wp[wave] = pc; }
    __syncthreads();
    if (threadIdx.x == 0) {
        const float csum = wc[0] + wc[1] + wc[2] + wc[3];
        const float rsum = wr[0] + wr[1] + wr[2] + wr[3];
        const float np = fmaxf((float)(wp[0] + wp[1] + wp[2] + wp[3]), 1.0f);
        out[0] = (csum + rsum) / np;
    }
}

extern "C" void kernel_launch(void* const* d_in, const int* in_sizes, int n_in,
                              void* d_out, int out_size, void* d_ws, size_t ws_size,
                              hipStream_t stream)
{
    const float* classification = (const float*)d_in[0];  // BB*AA*NC
    const float* regression     = (const float*)d_in[1];  // BB*AA*4
    const float* anchors        = (const float*)d_in[2];  // AA*4
    const float* annotations    = (const float*)d_in[3];  // BB*MM*5
    float* out = (float*)d_out;

    float*    cls_part = (float*)d_ws;
    float*    reg_part = cls_part + NBLK;
    unsigned* pos_part = (unsigned*)(reg_part + NBLK);

    dim3 grid(GX, BB);
    fused_kernel<<<grid, 256, 0, stream>>>(anchors, annotations, regression,
                                           classification, cls_part, reg_part, pos_part);
    finalize_kernel<<<1, 256, 0, stream>>>(cls_part, reg_part, pos_part, out);
}

// Round 5
// 202.866 us; speedup vs baseline: 1.5800x; 1.0227x over previous
//
#include <hip/hip_runtime.h>

#define BB 4
#define AA 100000
#define MM 32
#define NC 80
#define GX 391               // ceil(AA/256)
#define NBLK (GX * BB)       // 1564 blocks

// ws layout (floats): cls_part[NBLK] | reg_part[NBLK] | pos_part[NBLK] (as uint)
// All partials written unconditionally by every block -> no zero-init, no atomics.

__global__ __launch_bounds__(256) void fused_kernel(
    const float* __restrict__ anchors,      // AA*4
    const float* __restrict__ annotations,  // BB*MM*5
    const float* __restrict__ regression,   // BB*AA*4
    const float* __restrict__ cls,          // BB*AA*NC, read as float4
    float* __restrict__ cls_part,
    float* __restrict__ reg_part,
    unsigned* __restrict__ pos_part)
{
    __shared__ float ann[MM * 5];
    __shared__ int scode[256];   // -2 = excluded/fake, -1 = valid negative, 0..79 = positive class
    const int b = blockIdx.y;
    const int tid = threadIdx.x;
    if (tid < MM * 5) ann[tid] = annotations[b * MM * 5 + tid];
    __syncthreads();

    const int abase = blockIdx.x * 256;
    const int a = abase + tid;
    float reg_sum = 0.0f;
    int pos_cnt = 0;
    int code = -2;

    if (a < AA) {
        const float4 an = ((const float4*)anchors)[a];
        const float ax1 = an.x, ay1 = an.y, ax2 = an.z, ay2 = an.w;
        // exact IEEE ops (no FMA contraction) so pos/ignore thresholds match numpy bit-for-bit:
        const float area_a = __fmul_rn(__fsub_rn(ax2, ax1), __fsub_rn(ay2, ay1));

        float best_iou = -1.0f;
        int best = 0;
        #pragma unroll
        for (int j = 0; j < MM; ++j) {
            const float bx1 = ann[j * 5 + 0];
            const float by1 = ann[j * 5 + 1];
            const float bx2 = ann[j * 5 + 2];
            const float by2 = ann[j * 5 + 3];
            const float ix1 = fmaxf(ax1, bx1);
            const float iy1 = fmaxf(ay1, by1);
            const float ix2 = fminf(ax2, bx2);
            const float iy2 = fminf(ay2, by2);
            const float iw = fmaxf(__fsub_rn(ix2, ix1), 0.0f);
            const float ih = fmaxf(__fsub_rn(iy2, iy1), 0.0f);
            const float inter = __fmul_rn(iw, ih);
            const float area_b = __fmul_rn(__fsub_rn(bx2, bx1), __fsub_rn(by2, by1));
            const float uni = __fsub_rn(__fadd_rn(area_a, area_b), inter);
            const float iou = __fdiv_rn(inter, fmaxf(uni, 1e-8f));
            if (iou > best_iou) { best_iou = iou; best = j; }  // strict > keeps first max (argmax)
        }

        const bool pos = best_iou >= 0.5f;
        const bool ign = (best_iou > 0.4f) && !pos;
        const float cx = (ax1 + ax2) * 0.5f;
        const float cy = (ay1 + ay2) * 0.5f;
        const bool inside = (cx >= 0.0f) && (cx < 800.0f) && (cy >= 0.0f) && (cy < 800.0f);

        const bool valid = inside && !ign;      // state != -1
        if (valid) code = pos ? (int)ann[best * 5 + 4] : -1;

        if (pos && inside) {                    // state == 1
            pos_cnt = 1;
            const float aw = ax2 - ax1;
            const float ah = ay2 - ay1;
            const float bx1 = ann[best * 5 + 0];
            const float by1 = ann[best * 5 + 1];
            const float bx2 = ann[best * 5 + 2];
            const float by2 = ann[best * 5 + 3];
            float t[4];
            t[0] = ((bx1 - ax1) / aw) / 0.2f;
            t[1] = ((by1 - ay1) / ah) / 0.2f;
            t[2] = ((bx2 - ax2) / aw) / 0.2f;
            t[3] = ((by2 - ay2) / ah) / 0.2f;
            const float* rg = regression + (((size_t)b * AA + a) * 4);
            #pragma unroll
            for (int k = 0; k < 4; ++k) {
                const float d = fabsf(rg[k] - t[k]);
                reg_sum += (d < (1.0f / 9.0f)) ? (4.5f * d * d) : (d - (0.5f / 9.0f));
            }
        }
    }
    scode[tid] = code;
    __syncthreads();

    // ---- focal phase: pure unconditional stream ----
    // Block owns 5120 contiguous float4s. Thread t, step r -> flat = r*256+t
    // (coalesced). Address is affine in (r,tid) with only a `min` clamp for the
    // single partial block (OOB lanes collapse to one broadcast address).
    // NOTHING data-dependent sits on the address path: loads issue in clean
    // batches of 5. Validity/positive handling applied afterwards:
    //   csum += mask * focal_neg(all 4)   (mask = 0 only for ~1% ignored)
    //   rare branch adds focal_pos - focal_neg for the one labeled column.
    float csum = 0.0f;
    const float4* base4 = (const float4*)cls + ((size_t)b * AA + abase) * 20;
    const int maxflat = (abase + 256 <= AA) ? (5120 - 1) : ((AA - abase) * 20 - 1);

    #pragma unroll
    for (int batch = 0; batch < 4; ++batch) {
        float4 v[5];
        #pragma unroll
        for (int k = 0; k < 5; ++k) {
            const int flat = (batch * 5 + k) * 256 + tid;
            v[k] = base4[min(flat, maxflat)];
        }
        #pragma unroll
        for (int k = 0; k < 5; ++k) {
            const int flat = (batch * 5 + k) * 256 + tid;
            const int s = flat / 20;             // magic-mul
            const int colb = (flat - s * 20) * 4;
            const int c = scode[s];
            const float m = (c != -2) ? 1.0f : 0.0f;
            const float px[4] = { v[k].x, v[k].y, v[k].z, v[k].w };
            float pc[4];
            float sub = 0.0f;
            #pragma unroll
            for (int j = 0; j < 4; ++j) {
                const float p = fminf(fmaxf(px[j], 1e-4f), 0.9999f);
                pc[j] = p;
                sub += 0.75f * p * p * (-__logf(1.0f - p));        // label==0 form
            }
            csum += m * sub;
            const unsigned rel = (unsigned)(c - colb);
            if (rel < 4u) {                                        // rare: labeled column here
                const float p = pc[rel];
                const float onem = 1.0f - p;
                csum += 0.25f * onem * onem * (-__logf(p))         // add label==1 term
                      - 0.75f * p * p * (-__logf(onem));           // remove label==0 term
            }
        }
    }

    // ---- block reduction (wave shuffle + LDS), plain stores, no atomics ----
    #pragma unroll
    for (int off = 32; off > 0; off >>= 1) {
        csum    += __shfl_down(csum, off);
        reg_sum += __shfl_down(reg_sum, off);
        pos_cnt += __shfl_down(pos_cnt, off);
    }
    __shared__ float wc[4], wr[4];
    __shared__ int   wp[4];
    const int wave = tid >> 6, lane = tid & 63;
    if (lane == 0) { wc[wave] = csum; wr[wave] = reg_sum; wp[wave] = pos_cnt; }
    __syncthreads();
    if (tid == 0) {
        const int idx = b * GX + blockIdx.x;
        cls_part[idx] = wc[0] + wc[1] + wc[2] + wc[3];
        reg_part[idx] = wr[0] + wr[1] + wr[2] + wr[3];
        pos_part[idx] = (unsigned)(wp[0] + wp[1] + wp[2] + wp[3]);
    }
}

__global__ __launch_bounds__(256) void finalize_kernel(
    const float* __restrict__ cls_part,
    const float* __restrict__ reg_part,
    const unsigned* __restrict__ pos_part,
    float* __restrict__ out)
{
    float cs = 0.0f, rs = 0.0f;
    unsigned pc = 0;
    for (int i = threadIdx.x; i < NBLK; i += 256) {
        cs += cls_part[i];
        rs += reg_part[i];
        pc += pos_part[i];
    }
    #pragma unroll
    for (int off = 32; off > 0; off >>= 1) {
        cs += __shfl_down(cs, off);
        rs += __shfl_down(rs, off);
        pc += __shfl_down(pc, off);
    }
    __shared__ float wc[4], wr[4];
    __shared__ unsigned wp[4];
    const int wave = threadIdx.x >> 6, lane = threadIdx.x & 63;
    if (lane == 0) { wc[wave] = cs; wr[wave] = rs; wp[wave] = pc; }
    __syncthreads();
    if (threadIdx.x == 0) {
        const float csum = wc[0] + wc[1] + wc[2] + wc[3];
        const float rsum = wr[0] + wr[1] + wr[2] + wr[3];
        const float np = fmaxf((float)(wp[0] + wp[1] + wp[2] + wp[3]), 1.0f);
        out[0] = (csum + rsum) / np;
    }
}

extern "C" void kernel_launch(void* const* d_in, const int* in_sizes, int n_in,
                              void* d_out, int out_size, void* d_ws, size_t ws_size,
                              hipStream_t stream)
{
    const float* classification = (const float*)d_in[0];  // BB*AA*NC
    const float* regression     = (const float*)d_in[1];  // BB*AA*4
    const float* anchors        = (const float*)d_in[2];  // AA*4
    const float* annotations    = (const float*)d_in[3];  // BB*MM*5
    float* out = (float*)d_out;

    float*    cls_part = (float*)d_ws;
    float*    reg_part = cls_part + NBLK;
    unsigned* pos_part = (unsigned*)(reg_part + NBLK);

    dim3 grid(GX, BB);
    fused_kernel<<<grid, 256, 0, stream>>>(anchors, annotations, regression,
                                           classification, cls_part, reg_part, pos_part);
    finalize_kernel<<<1, 256, 0, stream>>>(cls_part, reg_part, pos_part, out);
}